// Round 3
// baseline (77.512 us; speedup 1.0000x reference)
//
#include <hip/hip_runtime.h>
#include <hip/hip_bf16.h>

typedef float f32x4 __attribute__((ext_vector_type(4)));
typedef __bf16 bf16x8 __attribute__((ext_vector_type(8)));
typedef __bf16 bf16x4 __attribute__((ext_vector_type(4)));

#define DEMB 128
#define HIDDEN 64
#define W1T_STRIDE 264   // fallback kernel only

// ---------------- Phase 1: per-node partials (dense skinny GEMM, bf16 out) ----
// spart[n][:] = src_embs[n] @ W1[0:128, :]   (bf16)
// dpart[n][:] = dst_embs[n] @ W1[128:256, :] (bf16)
// W1 half staged in LDS pre-arranged in exact MFMA-fragment order:
// chunk cid = t*256 + kk*64 + gk*16 + el  (16B = bf16x8), lane reads lds[lane*16B]
// => conflict-free ds_read_b128. N-tile mapping n = 4*el + t so each lane's 4
// accumulators are consecutive hidden units -> one bf16x4 (8B) store per row.
__global__ __launch_bounds__(256, 8) void node_part2_kernel(
    const float* __restrict__ src_embs,
    const float* __restrict__ dst_embs,
    const float* __restrict__ W1,
    __bf16* __restrict__ spart,
    __bf16* __restrict__ dpart,
    int n_tiles, int blocks_per_table)
{
    __shared__ __bf16 frag_lds[1024 * 8];   // 16 KB

    const int table = (blockIdx.x >= blocks_per_table) ? 1 : 0;
    const int bid = blockIdx.x - table * blocks_per_table;
    const float* __restrict__ E = table ? dst_embs : src_embs;
    __bf16* __restrict__ P = table ? dpart : spart;
    const int kofs = table * 128;

    // Stage this table's W1 half into fragment-ordered LDS (one-time).
    for (int cid = threadIdx.x; cid < 1024; cid += 256) {
        const int el = cid & 15;
        const int gk = (cid >> 4) & 3;
        const int kk = (cid >> 6) & 3;
        const int t  = (cid >> 8) & 3;
        const int kbase = kofs + kk * 32 + gk * 8;
        bf16x8 ch;
#pragma unroll
        for (int j = 0; j < 8; ++j)
            ch[j] = (__bf16)W1[(kbase + j) * HIDDEN + 4 * el + t];
        *reinterpret_cast<bf16x8*>(&frag_lds[cid * 8]) = ch;
    }
    __syncthreads();

    const int lane = threadIdx.x & 63;
    const int el = lane & 15;   // node-within-tile (A row) / B col group
    const int gk = lane >> 4;   // k-subgroup
    const int wid = threadIdx.x >> 6;

    for (int tile = bid * 4 + wid; tile < n_tiles; tile += blocks_per_table * 4) {
        const int nbase = tile * 16;
        const float* rp = E + (size_t)(nbase + el) * DEMB + gk * 8;

        f32x4 acc[4] = {{0.f,0.f,0.f,0.f},{0.f,0.f,0.f,0.f},
                        {0.f,0.f,0.f,0.f},{0.f,0.f,0.f,0.f}};
#pragma unroll
        for (int kk = 0; kk < 4; ++kk) {
            f32x4 f0 = *reinterpret_cast<const f32x4*>(rp + kk * 32);
            f32x4 f1 = *reinterpret_cast<const f32x4*>(rp + kk * 32 + 4);
            bf16x8 a;
#pragma unroll
            for (int j = 0; j < 4; ++j) { a[j] = (__bf16)f0[j]; a[4+j] = (__bf16)f1[j]; }
#pragma unroll
            for (int t = 0; t < 4; ++t) {
                const bf16x8 b = *reinterpret_cast<const bf16x8*>(
                    &frag_lds[(size_t)((t * 4 + kk) * 4 + gk) * 128 + el * 8]);
                acc[t] = __builtin_amdgcn_mfma_f32_16x16x32_bf16(a, b, acc[t], 0, 0, 0);
            }
        }
        // C/D: col = el -> units 4*el+t (consecutive); row = gk*4 + r (node)
#pragma unroll
        for (int r = 0; r < 4; ++r) {
            bf16x4 pk;
#pragma unroll
            for (int t = 0; t < 4; ++t) pk[t] = (__bf16)acc[t][r];
            *reinterpret_cast<bf16x4*>(
                P + (size_t)(nbase + gk * 4 + r) * HIDDEN + 4 * el) = pk;
        }
    }
}

// ---------------- Phase 2: per-edge gather of bf16 partials + MLP tail --------
__global__ __launch_bounds__(256, 8) void edge_tail2_kernel(
    const __bf16* __restrict__ spart,
    const __bf16* __restrict__ dpart,
    const int* __restrict__ src_ids,
    const int* __restrict__ dst_ids,
    const float* __restrict__ b1,
    const float* __restrict__ W2,
    const float* __restrict__ b2,
    float* __restrict__ out,
    int n_edges)
{
    const int lane = threadIdx.x & 63;
    const int c = lane & 7;           // bf16x8 chunk within hidden dim
    float b1v[8], w2v[8];
#pragma unroll
    for (int j = 0; j < 8; ++j) { b1v[j] = b1[c * 8 + j]; w2v[j] = W2[c * 8 + j]; }
    const float bias2 = b2[0];

    int gid = (blockIdx.x * blockDim.x + threadIdx.x) >> 3;   // one edge per 8 lanes
    const int gstride = (gridDim.x * blockDim.x) >> 3;

    for (int e = gid; e < n_edges; e += gstride) {
        const long long sid = src_ids[e];
        const long long did = dst_ids[e];
        const bf16x8 s8 = *reinterpret_cast<const bf16x8*>(spart + sid * HIDDEN + c * 8);
        const bf16x8 d8 = *reinterpret_cast<const bf16x8*>(dpart + did * HIDDEN + c * 8);
        float v = 0.f;
#pragma unroll
        for (int j = 0; j < 8; ++j) {
            float h = (float)s8[j] + (float)d8[j] + b1v[j];
            h = fmaxf(h, 0.f);
            v = fmaf(h, w2v[j], v);
        }
        v += __shfl_xor(v, 1, 64);
        v += __shfl_xor(v, 2, 64);
        v += __shfl_xor(v, 4, 64);
        if (c == 0) out[e] = v + bias2;
    }
}

// ---------------- Fallback (round-1 proven kernel) if ws too small ------------
__global__ __launch_bounds__(256) void edge_mlp_kernel(
    const float* __restrict__ src_embs,
    const float* __restrict__ dst_embs,
    const int* __restrict__ src_ids,
    const int* __restrict__ dst_ids,
    const float* __restrict__ W1,
    const float* __restrict__ b1,
    const float* __restrict__ W2,
    const float* __restrict__ b2,
    float* __restrict__ out,
    int n_edges, int n_groups)
{
    __shared__ __bf16 w1t[64 * W1T_STRIDE];
    for (int s = threadIdx.x; s < 256 * 64; s += 256) {
        int k = s >> 6;
        int n = s & 63;
        w1t[n * W1T_STRIDE + k] = (__bf16)W1[s];
    }
    __syncthreads();

    const int lane = threadIdx.x & 63;
    const int el = lane & 15;
    const int gk = lane >> 4;

    float b1v[4], w2v[4];
#pragma unroll
    for (int t = 0; t < 4; ++t) { b1v[t] = b1[16 * t + el]; w2v[t] = W2[16 * t + el]; }
    const float bias2 = b2[0];

    const int gw0 = blockIdx.x * 4 + (threadIdx.x >> 6);
    const int gstride = gridDim.x * 4;

    for (int g = gw0; g < n_groups; g += gstride) {
        const int e_base = g * 16;
        int e = e_base + el;
        if (e >= n_edges) e = n_edges - 1;
        const long long sid = src_ids[e];
        const long long did = dst_ids[e];
        const float* sp = src_embs + sid * DEMB + gk * 8;
        const float* dp = dst_embs + did * DEMB + gk * 8;

        f32x4 acc[4] = {{0.f,0.f,0.f,0.f},{0.f,0.f,0.f,0.f},
                        {0.f,0.f,0.f,0.f},{0.f,0.f,0.f,0.f}};
#pragma unroll
        for (int kk = 0; kk < 8; ++kk) {
            const float* ap = (kk < 4) ? (sp + kk * 32) : (dp + (kk - 4) * 32);
            f32x4 f0 = *reinterpret_cast<const f32x4*>(ap);
            f32x4 f1 = *reinterpret_cast<const f32x4*>(ap + 4);
            bf16x8 a;
#pragma unroll
            for (int j = 0; j < 4; ++j) { a[j] = (__bf16)f0[j]; a[4+j] = (__bf16)f1[j]; }
#pragma unroll
            for (int t = 0; t < 4; ++t) {
                const bf16x8 bfrag = *reinterpret_cast<const bf16x8*>(
                    &w1t[(16 * t + el) * W1T_STRIDE + kk * 32 + gk * 8]);
                acc[t] = __builtin_amdgcn_mfma_f32_16x16x32_bf16(a, bfrag, acc[t], 0, 0, 0);
            }
        }
        float s0[4];
#pragma unroll
        for (int r = 0; r < 4; ++r) {
            float v = 0.f;
#pragma unroll
            for (int t = 0; t < 4; ++t) {
                float h = acc[t][r] + b1v[t];
                h = fmaxf(h, 0.f);
                v = fmaf(h, w2v[t], v);
            }
#pragma unroll
            for (int m = 1; m < 16; m <<= 1) v += __shfl_xor(v, m, 64);
            s0[r] = v + bias2;
        }
        const int row0 = e_base + gk * 4;
        if (el == 0) {
            if (row0 + 4 <= n_edges) {
                f32x4 o = {s0[0], s0[1], s0[2], s0[3]};
                *reinterpret_cast<f32x4*>(out + row0) = o;
            } else {
#pragma unroll
                for (int r = 0; r < 4; ++r)
                    if (row0 + r < n_edges) out[row0 + r] = s0[r];
            }
        }
    }
}

extern "C" void kernel_launch(void* const* d_in, const int* in_sizes, int n_in,
                              void* d_out, int out_size, void* d_ws, size_t ws_size,
                              hipStream_t stream) {
    const float* src_embs = (const float*)d_in[0];
    const float* dst_embs = (const float*)d_in[1];
    const int*   src_ids  = (const int*)d_in[2];
    const int*   dst_ids  = (const int*)d_in[3];
    const float* W1 = (const float*)d_in[4];
    const float* b1 = (const float*)d_in[5];
    const float* W2 = (const float*)d_in[6];
    const float* b2 = (const float*)d_in[7];
    float* out = (float*)d_out;

    const int n_edges = in_sizes[2];
    const int n_nodes = in_sizes[0] / DEMB;                   // 100000
    const size_t part_elems = (size_t)n_nodes * HIDDEN;
    const size_t need = 2 * part_elems * sizeof(__bf16);      // 25.6 MB

    if (ws_size >= need && (n_nodes % 16) == 0) {
        __bf16* spart = (__bf16*)d_ws;
        __bf16* dpart = spart + part_elems;
        const int n_tiles = n_nodes / 16;                     // 6250

        // 1024 blocks per table -> 2048 total = 8 blocks/CU (16KB LDS allows 10)
        int bpt = 1024;
        if (bpt * 4 > n_tiles) bpt = (n_tiles + 3) / 4;
        node_part2_kernel<<<2 * bpt, 256, 0, stream>>>(
            src_embs, dst_embs, W1, spart, dpart, n_tiles, bpt);

        int blocks2 = (n_edges + 31) / 32;                    // 32 edges / block-iter
        if (blocks2 > 2048) blocks2 = 2048;
        edge_tail2_kernel<<<blocks2, 256, 0, stream>>>(
            spart, dpart, src_ids, dst_ids, b1, W2, b2, out, n_edges);
    } else {
        const int n_groups = (n_edges + 15) / 16;
        int blocks = (n_groups + 3) / 4;
        if (blocks > 1024) blocks = 1024;
        edge_mlp_kernel<<<blocks, 256, 0, stream>>>(
            src_embs, dst_embs, src_ids, dst_ids, W1, b1, W2, b2, out,
            n_edges, n_groups);
    }
}

// Round 4
// 40.368 us; speedup vs baseline: 1.9201x; 1.9201x over previous
//
#include <hip/hip_runtime.h>
#include <hip/hip_bf16.h>

typedef float f32x4 __attribute__((ext_vector_type(4)));
typedef __bf16 bf16x8 __attribute__((ext_vector_type(8)));
typedef __bf16 bf16x4 __attribute__((ext_vector_type(4)));

#define DEMB 128
#define HIDDEN 64
#define W1T_STRIDE 264   // fallback kernel only

typedef const __attribute__((address_space(1))) void* gas_ptr;
typedef __attribute__((address_space(3))) void* las_ptr;

// ---------------- Phase 1: per-node partials via global_load_lds staging ------
// Tile = 16 consecutive nodes = 8 KB contiguous f32.
// Stage linearly into per-wave LDS region with pre-swizzled global source:
//   LDS[d] = global[d ^ (((d>>9)&7)<<4)]   (XOR row-bits 9-11 into 16B-slot bits 4-6)
// Fragment read applies the same XOR -> spread banks. Output tile (16x64 bf16 = 2KB)
// bounced through the same LDS region, then copied out linearly (32 B/lane).
__global__ __launch_bounds__(256) void node_part3_kernel(
    const float* __restrict__ src_embs,
    const float* __restrict__ dst_embs,
    const float* __restrict__ W1,
    __bf16* __restrict__ spart,
    __bf16* __restrict__ dpart,
    int n_tiles, int blocks_per_table)
{
    __shared__ __bf16 frag_lds[1024 * 8];   // 16 KB: W1-half in MFMA-fragment order
    __shared__ float  atile[4][2048];       // 4 waves x 8 KB staging/bounce

    const int table = (blockIdx.x >= blocks_per_table) ? 1 : 0;
    const int bid = blockIdx.x - table * blocks_per_table;
    const float* __restrict__ E = table ? dst_embs : src_embs;
    __bf16* __restrict__ P = table ? dpart : spart;
    const int kofs = table * 128;

    // Stage this table's W1 half into fragment-ordered LDS (R3-proven: 0 conflicts).
    for (int cid = threadIdx.x; cid < 1024; cid += 256) {
        const int el = cid & 15;
        const int gk = (cid >> 4) & 3;
        const int kk = (cid >> 6) & 3;
        const int t  = (cid >> 8) & 3;
        const int kbase = kofs + kk * 32 + gk * 8;
        bf16x8 ch;
#pragma unroll
        for (int j = 0; j < 8; ++j)
            ch[j] = (__bf16)W1[(kbase + j) * HIDDEN + 4 * el + t];
        *reinterpret_cast<bf16x8*>(&frag_lds[cid * 8]) = ch;
    }
    __syncthreads();

    const int lane = threadIdx.x & 63;
    const int el = lane & 15;
    const int gk = lane >> 4;
    const int wid = threadIdx.x >> 6;
    char* awc = (char*)&atile[wid][0];

    // Pre-swizzled global source offsets (involution: XOR bits 4-6 with bits 9-11).
    int soff[8];
#pragma unroll
    for (int op = 0; op < 8; ++op) {
        const int d = op * 1024 + lane * 16;
        soff[op] = d ^ (((d >> 9) & 7) << 4);
    }
    // Swizzled per-lane A-fragment base (tile byte el*512 + gk*32).
    const int abase = (el * 512 + gk * 32) ^ ((el & 7) << 4);

    const int tstride = blocks_per_table * 4;
    for (int tile = bid * 4 + wid; tile < n_tiles; tile += tstride) {
        const char* ebase = (const char*)E + (size_t)tile * (16 * DEMB * 4);
#pragma unroll
        for (int op = 0; op < 8; ++op) {
            __builtin_amdgcn_global_load_lds(
                (gas_ptr)(ebase + soff[op]),
                (las_ptr)(awc + op * 1024), 16, 0, 0);
        }
        asm volatile("s_waitcnt vmcnt(0)" ::: "memory");

        f32x4 acc[4] = {{0.f,0.f,0.f,0.f},{0.f,0.f,0.f,0.f},
                        {0.f,0.f,0.f,0.f},{0.f,0.f,0.f,0.f}};
#pragma unroll
        for (int kk = 0; kk < 4; ++kk) {
            const int ab = abase + kk * 128;
            f32x4 lo = *reinterpret_cast<const f32x4*>(awc + ab);
            f32x4 hi = *reinterpret_cast<const f32x4*>(awc + (ab ^ 16));
            bf16x8 a;
#pragma unroll
            for (int j = 0; j < 4; ++j) { a[j] = (__bf16)lo[j]; a[4+j] = (__bf16)hi[j]; }
#pragma unroll
            for (int t = 0; t < 4; ++t) {
                const bf16x8 b = *reinterpret_cast<const bf16x8*>(
                    &frag_lds[(size_t)((t * 4 + kk) * 4 + gk) * 128 + el * 8]);
                acc[t] = __builtin_amdgcn_mfma_f32_16x16x32_bf16(a, b, acc[t], 0, 0, 0);
            }
        }

        // Bounce output tile (16 rows x 64 bf16 = 2 KB) through LDS, reuse A region.
        asm volatile("" ::: "memory");
#pragma unroll
        for (int r = 0; r < 4; ++r) {
            bf16x4 pk;
#pragma unroll
            for (int t = 0; t < 4; ++t) pk[t] = (__bf16)acc[t][r];
            *reinterpret_cast<bf16x4*>(awc + (gk * 4 + r) * 128 + el * 8) = pk;
        }
        asm volatile("s_waitcnt lgkmcnt(0)" ::: "memory");
        // Linear copy-out: 64 lanes x 32 B = 2 KB contiguous -> full-line writes.
        f32x4 c0 = *reinterpret_cast<const f32x4*>(awc + lane * 32);
        f32x4 c1 = *reinterpret_cast<const f32x4*>(awc + lane * 32 + 16);
        char* pb = (char*)P + (size_t)tile * 2048;
        *reinterpret_cast<f32x4*>(pb + lane * 32) = c0;
        *reinterpret_cast<f32x4*>(pb + lane * 32 + 16) = c1;
    }
}

// ---------------- Phase 2: per-edge gather of bf16 partials + MLP tail --------
__global__ __launch_bounds__(256, 8) void edge_tail2_kernel(
    const __bf16* __restrict__ spart,
    const __bf16* __restrict__ dpart,
    const int* __restrict__ src_ids,
    const int* __restrict__ dst_ids,
    const float* __restrict__ b1,
    const float* __restrict__ W2,
    const float* __restrict__ b2,
    float* __restrict__ out,
    int n_edges)
{
    const int lane = threadIdx.x & 63;
    const int c = lane & 7;           // bf16x8 chunk within hidden dim
    float b1v[8], w2v[8];
#pragma unroll
    for (int j = 0; j < 8; ++j) { b1v[j] = b1[c * 8 + j]; w2v[j] = W2[c * 8 + j]; }
    const float bias2 = b2[0];

    int gid = (blockIdx.x * blockDim.x + threadIdx.x) >> 3;   // one edge per 8 lanes
    const int gstride = (gridDim.x * blockDim.x) >> 3;

    for (int e = gid; e < n_edges; e += gstride) {
        const long long sid = src_ids[e];
        const long long did = dst_ids[e];
        const bf16x8 s8 = *reinterpret_cast<const bf16x8*>(spart + sid * HIDDEN + c * 8);
        const bf16x8 d8 = *reinterpret_cast<const bf16x8*>(dpart + did * HIDDEN + c * 8);
        float v = 0.f;
#pragma unroll
        for (int j = 0; j < 8; ++j) {
            float h = (float)s8[j] + (float)d8[j] + b1v[j];
            h = fmaxf(h, 0.f);
            v = fmaf(h, w2v[j], v);
        }
        v += __shfl_xor(v, 1, 64);
        v += __shfl_xor(v, 2, 64);
        v += __shfl_xor(v, 4, 64);
        if (c == 0) out[e] = v + bias2;
    }
}

// ---------------- Fallback (round-1 proven kernel) if ws too small ------------
__global__ __launch_bounds__(256) void edge_mlp_kernel(
    const float* __restrict__ src_embs,
    const float* __restrict__ dst_embs,
    const int* __restrict__ src_ids,
    const int* __restrict__ dst_ids,
    const float* __restrict__ W1,
    const float* __restrict__ b1,
    const float* __restrict__ W2,
    const float* __restrict__ b2,
    float* __restrict__ out,
    int n_edges, int n_groups)
{
    __shared__ __bf16 w1t[64 * W1T_STRIDE];
    for (int s = threadIdx.x; s < 256 * 64; s += 256) {
        int k = s >> 6;
        int n = s & 63;
        w1t[n * W1T_STRIDE + k] = (__bf16)W1[s];
    }
    __syncthreads();

    const int lane = threadIdx.x & 63;
    const int el = lane & 15;
    const int gk = lane >> 4;

    float b1v[4], w2v[4];
#pragma unroll
    for (int t = 0; t < 4; ++t) { b1v[t] = b1[16 * t + el]; w2v[t] = W2[16 * t + el]; }
    const float bias2 = b2[0];

    const int gw0 = blockIdx.x * 4 + (threadIdx.x >> 6);
    const int gstride = gridDim.x * 4;

    for (int g = gw0; g < n_groups; g += gstride) {
        const int e_base = g * 16;
        int e = e_base + el;
        if (e >= n_edges) e = n_edges - 1;
        const long long sid = src_ids[e];
        const long long did = dst_ids[e];
        const float* sp = src_embs + sid * DEMB + gk * 8;
        const float* dp = dst_embs + did * DEMB + gk * 8;

        f32x4 acc[4] = {{0.f,0.f,0.f,0.f},{0.f,0.f,0.f,0.f},
                        {0.f,0.f,0.f,0.f},{0.f,0.f,0.f,0.f}};
#pragma unroll
        for (int kk = 0; kk < 8; ++kk) {
            const float* ap = (kk < 4) ? (sp + kk * 32) : (dp + (kk - 4) * 32);
            f32x4 f0 = *reinterpret_cast<const f32x4*>(ap);
            f32x4 f1 = *reinterpret_cast<const f32x4*>(ap + 4);
            bf16x8 a;
#pragma unroll
            for (int j = 0; j < 4; ++j) { a[j] = (__bf16)f0[j]; a[4+j] = (__bf16)f1[j]; }
#pragma unroll
            for (int t = 0; t < 4; ++t) {
                const bf16x8 bfrag = *reinterpret_cast<const bf16x8*>(
                    &w1t[(16 * t + el) * W1T_STRIDE + kk * 32 + gk * 8]);
                acc[t] = __builtin_amdgcn_mfma_f32_16x16x32_bf16(a, bfrag, acc[t], 0, 0, 0);
            }
        }
        float s0[4];
#pragma unroll
        for (int r = 0; r < 4; ++r) {
            float v = 0.f;
#pragma unroll
            for (int t = 0; t < 4; ++t) {
                float h = acc[t][r] + b1v[t];
                h = fmaxf(h, 0.f);
                v = fmaf(h, w2v[t], v);
            }
#pragma unroll
            for (int m = 1; m < 16; m <<= 1) v += __shfl_xor(v, m, 64);
            s0[r] = v + bias2;
        }
        const int row0 = e_base + gk * 4;
        if (el == 0) {
            if (row0 + 4 <= n_edges) {
                f32x4 o = {s0[0], s0[1], s0[2], s0[3]};
                *reinterpret_cast<f32x4*>(out + row0) = o;
            } else {
#pragma unroll
                for (int r = 0; r < 4; ++r)
                    if (row0 + r < n_edges) out[row0 + r] = s0[r];
            }
        }
    }
}

extern "C" void kernel_launch(void* const* d_in, const int* in_sizes, int n_in,
                              void* d_out, int out_size, void* d_ws, size_t ws_size,
                              hipStream_t stream) {
    const float* src_embs = (const float*)d_in[0];
    const float* dst_embs = (const float*)d_in[1];
    const int*   src_ids  = (const int*)d_in[2];
    const int*   dst_ids  = (const int*)d_in[3];
    const float* W1 = (const float*)d_in[4];
    const float* b1 = (const float*)d_in[5];
    const float* W2 = (const float*)d_in[6];
    const float* b2 = (const float*)d_in[7];
    float* out = (float*)d_out;

    const int n_edges = in_sizes[2];
    const int n_nodes = in_sizes[0] / DEMB;                   // 100000
    const size_t part_elems = (size_t)n_nodes * HIDDEN;
    const size_t need = 2 * part_elems * sizeof(__bf16);      // 25.6 MB

    if (ws_size >= need && (n_nodes % 16) == 0) {
        __bf16* spart = (__bf16*)d_ws;
        __bf16* dpart = spart + part_elems;
        const int n_tiles = n_nodes / 16;                     // 6250

        int bpt = 384;                                        // 768 blocks = 3/CU
        if (bpt * 4 > n_tiles) bpt = (n_tiles + 3) / 4;
        node_part3_kernel<<<2 * bpt, 256, 0, stream>>>(
            src_embs, dst_embs, W1, spart, dpart, n_tiles, bpt);

        int blocks2 = (n_edges + 31) / 32;
        if (blocks2 > 2048) blocks2 = 2048;
        edge_tail2_kernel<<<blocks2, 256, 0, stream>>>(
            spart, dpart, src_ids, dst_ids, b1, W2, b2, out, n_edges);
    } else {
        const int n_groups = (n_edges + 15) / 16;
        int blocks = (n_groups + 3) / 4;
        if (blocks > 1024) blocks = 1024;
        edge_mlp_kernel<<<blocks, 256, 0, stream>>>(
            src_embs, dst_embs, src_ids, dst_ids, W1, b1, W2, b2, out,
            n_edges, n_groups);
    }
}